// Round 9
// baseline (500.231 us; speedup 1.0000x reference)
//
#include <hip/hip_runtime.h>
#include <hip/hip_bf16.h>
#include <cmath>

#define T_STEPS 16
#define BATCH   512
#define N_IN    3072
#define S1      256
#define S2      256
#define S3      128
#define NEXP    8
#define M_ROWS  (T_STEPS * BATCH)   // 8192
#define MT_ALL  (M_ROWS / 32)       // 256 m-tiles

typedef int v4i  __attribute__((ext_vector_type(4)));
typedef int v16i __attribute__((ext_vector_type(16)));
typedef unsigned long long u64;
typedef unsigned int uint32;

// ---------------------------------------------------------------------------
// bit->byte unpack: 16 bits -> 16 i8 (0/1). mul-free spread.
// ---------------------------------------------------------------------------
__device__ __forceinline__ v4i unpack16_bits(uint32 w16)
{
    v4i d;
    #pragma unroll
    for (int c = 0; c < 4; ++c) {
        uint32 x = (w16 >> (4 * c)) & 0xFu;
        x = x + (x << 7);
        x = x + (x << 14);
        d[c] = (int)(x & 0x01010101u);
    }
    return d;
}

// ---------------------------------------------------------------------------
// 4-limb weight digitize (stages 2/3). B-row gr = o*32 + e*4 + limb.
// ---------------------------------------------------------------------------
template<int S, int K>
__device__ __forceinline__ void digitize_chunk(
    const float* __restrict__ W, char* __restrict__ Bf, int t)
{
    int lane16 = t & 63;
    int o  = (t >> 6) & (S - 1);
    int kb = t >> ((S == 256) ? 14 : 13);
    int r  = lane16 & 31;
    int qd = lane16 >> 5;
    int e    = r >> 2;
    int limb = r & 3;
    int k0 = kb * 32 + qd * 16;

    const float4* Wp = (const float4*)(W + ((size_t)e * S + o) * K + k0);
    char out[16];
    #pragma unroll
    for (int f4 = 0; f4 < 4; ++f4) {
        float4 w = Wp[f4];
        float ws[4] = {w.x, w.y, w.z, w.w};
        #pragma unroll
        for (int c = 0; c < 4; ++c) {
            long long q = llrint((double)ws[c] * 4294967296.0);
            int d = 0;
            #pragma unroll
            for (int l = 0; l < 4; ++l) {
                int dl = (int)((q + 128) & 255) - 128;
                q = (q - dl) >> 8;
                if (l == limb) d = dl;
            }
            out[f4 * 4 + c] = (char)d;
        }
    }
    *(v4i*)(Bf + (size_t)t * 16) = *(v4i*)out;
}

// ---------------------------------------------------------------------------
// prep: pack x bits + 3-limb LIMB-MAJOR digitize W1 + 4-limb W2/W3.
// R9: W1 rows gr = limb*2048 + (o*8+e) -> the 3 limbs of one (o,e) occupy
// the SAME column position in 3 different n-tiles (jj = limb), so the GEMM
// epilogue recombines per-lane with no shuffles/atomics.
// ---------------------------------------------------------------------------
__global__ __launch_bounds__(256) void prep(
    const float* __restrict__ x,  const float* __restrict__ W1,
    const float* __restrict__ W2, const float* __restrict__ W3,
    u64* __restrict__ bitsT, char* __restrict__ B1f,
    char* __restrict__ B2f,  char* __restrict__ B3f)
{
    const int bid = blockIdx.x;
    const int tid = threadIdx.x;
    if (bid < 98304) {
        int gid = bid * 256 + tid;
        float v = x[gid];
        u64 m = __ballot(v >= 0.5f);
        if ((tid & 63) == 0) {
            int tb = gid / N_IN;                 // t*512 + b
            int k  = gid - tb * N_IN;
            int t  = tb >> 9;
            int b  = tb & 511;
            bitsT[(size_t)(k >> 6) * M_ROWS + (b * 16 + t)] = m;
        }
    } else if (bid < 98304 + 4608) {
        // W1 3-limb limb-major: chunks = 96 kb * 192 tiles * 64 l16
        int t    = (bid - 98304) * 256 + tid;
        int l16  = t & 63;
        int tt   = t >> 6;               // kb*192 + tile
        int tile = tt % 192;
        int kb   = tt / 192;
        int gr   = tile * 32 + (l16 & 31);
        int qd   = l16 >> 5;
        int limb = gr >> 11;             // 0..2
        int oe   = gr & 2047;
        int o    = oe >> 3;
        int e    = oe & 7;
        int k0   = kb * 32 + qd * 16;
        const float4* Wp = (const float4*)(W1 + ((size_t)e * S1 + o) * N_IN + k0);
        char out[16];
        #pragma unroll
        for (int f4 = 0; f4 < 4; ++f4) {
            float4 w = Wp[f4];
            float ws[4] = {w.x, w.y, w.z, w.w};
            #pragma unroll
            for (int c = 0; c < 4; ++c) {
                long long q = llrint((double)ws[c] * 16777216.0);
                int d0 = (int)((q + 128) & 255) - 128;
                long long q1 = (q - d0) >> 8;
                int d1 = (int)((q1 + 128) & 255) - 128;
                int d2 = (int)((q1 - d1) >> 8);
                int d  = (limb == 0) ? d0 : ((limb == 1) ? d1 : d2);
                out[f4 * 4 + c] = (char)d;
            }
        }
        *(v4i*)(B1f + (size_t)t * 16) = *(v4i*)out;
    } else if (bid < 98304 + 4608 + 512) {
        digitize_chunk<S2, S1>(W2, B2f, (bid - 98304 - 4608) * 256 + tid);
    } else {
        digitize_chunk<S3, S2>(W3, B3f, (bid - 98304 - 4608 - 512) * 256 + tid);
    }
}

// ---------------------------------------------------------------------------
// R9 stage 1: 3-limb limb-major GEMM + per-lane recombine + LIF.
// Block 128m x 96n(=32 oe x 3 limbs); wave tile 32m x 96n.
// R8 post-mortem: wall had ~675 cy/body-slot of stall (pipes 66% combined)
// from {atomic epilogue (6.3M bank conflicts), per-triple s_barrier, thin
// TLP}. R9: (1) limb-major -> epilogue is per-lane int+f64, no shuffles or
// atomics; (2) no barrier (R6-proven); (3) 4 waves/SIMD with distance-1
// double-buffer (R3-proven pattern; ~115 regs fits the 128 budget).
// B slab per XCD = 8 nblk * 288 KB = 2.25 MB < 4 MB L2; mblk-major keeps
// co-resident blocks on one slab (L1 dedup).
// ---------------------------------------------------------------------------
__global__ __launch_bounds__(256, 4) void fused_stage1(
    const u64* __restrict__ AT0, const char* __restrict__ Bf,
    const float* __restrict__ g, char* __restrict__ Cf,
    float* __restrict__ Mean)
{
    constexpr int KI      = N_IN / 64;       // 48 bodies
    constexpr int KSTRIDE = 192 * 1024;      // bytes per kb step (192 tiles)
    constexpr int BSTEP   = 2 * KSTRIDE;     // bytes per body (2 kb)
    __shared__ double hs[128 * 32];          // 32 KB

    const int tid  = threadIdx.x;
    const int lane = tid & 63;
    const int w    = tid >> 6;
    const int col  = lane & 31;
    const int qd   = lane >> 5;
    const int wm   = w * 32;

    // mblk-major XCD map: 64 nblk (8/XCD), 64 mblk
    const int id    = blockIdx.x;
    const int xcd   = id & 7;
    const int inner = id >> 3;
    const int nblk  = xcd * 8 + (inner >> 6);
    const int mblk  = inner & 63;
    const int m0    = mblk * 128;

    const u64* AT = AT0 + (m0 + wm + col);
    const int sh16 = qd * 16;
    // tile for (kb, limb jj) = kb*192 + jj*64 + nblk
    const char* Bu = Bf + (size_t)nblk * 1024 + lane * 16;

    v16i acc[3];
    #pragma unroll
    for (int j = 0; j < 3; ++j)
        #pragma unroll
        for (int r = 0; r < 16; ++r) acc[j][r] = 0;

    u64 ab[2];
    v4i Bb[2][6];

    // preload body 0 (distance-1)
    ab[0] = AT[0];
    #pragma unroll
    for (int ks = 0; ks < 2; ++ks)
        #pragma unroll
        for (int jj = 0; jj < 3; ++jj)
            Bb[0][ks * 3 + jj] =
                *(const v4i*)(Bu + ks * KSTRIDE + jj * 65536);

    auto body = [&](int it, int cur, int pf) {
        const int itp = it + 1;              // clamp-free (padded buffers)
        ab[pf] = AT[(size_t)itp * M_ROWS];
        const char* bu = Bu + (size_t)itp * BSTEP;
        #pragma unroll
        for (int ks = 0; ks < 2; ++ks)
            #pragma unroll
            for (int jj = 0; jj < 3; ++jj)
                Bb[pf][ks * 3 + jj] =
                    *(const v4i*)(bu + ks * KSTRIDE + jj * 65536);
        __builtin_amdgcn_s_setprio(1);
        #pragma unroll
        for (int ks = 0; ks < 2; ++ks) {
            uint32 dw = ks ? (uint32)(ab[cur] >> 32) : (uint32)ab[cur];
            v4i af = unpack16_bits(dw >> sh16);
            #pragma unroll
            for (int jj = 0; jj < 3; ++jj)
                acc[jj] = __builtin_amdgcn_mfma_i32_32x32x32_i8(
                    af, Bb[cur][ks * 3 + jj], acc[jj], 0, 0, 0);
        }
        __builtin_amdgcn_s_setprio(0);
    };

    for (int it = 0; it < KI; it += 2) {
        body(it + 0, 0, 1);
        body(it + 1, 1, 0);
    }

    // ---- per-lane exact recombine: limbs live in acc[0..2] of SAME lane ----
    // h = (acc0 + 256*acc1 + 65536*acc2) * 2^-24; |acc_l| < 2^19 -> exact.
    const double sc = 1.0 / 16777216.0;
    #pragma unroll
    for (int reg = 0; reg < 16; ++reg) {
        int m  = wm + (reg & 3) + 8 * (reg >> 2) + 4 * qd;
        int lo = acc[0][reg] + (acc[1][reg] << 8);
        double d = ((double)lo + 65536.0 * (double)acc[2][reg]) * sc;
        hs[m * 32 + col] = d;
    }
    __syncthreads();

    // ---- LIF: thread = (b_loc = tid>>5, oe = tid&31) ----
    const int b_loc = tid >> 5;
    const int oe    = tid & 31;
    const int o_loc = oe >> 3;
    const int e     = tid & 7;
    const float ge  = g[e];
    const int bg = mblk * 8 + b_loc;
    const int og = nblk * 4 + o_loc;

    const int kb_a   = og >> 5;
    const int qd_a   = (og >> 4) & 1;
    const int byte_a = og & 15;

    double v = 0.0;
    float gacc = 0.0f;
    #pragma unroll
    for (int t = 0; t < T_STEPS; ++t) {
        double h  = hs[(b_loc * 16 + t) * 32 + oe];
        double vv = v * 0.95 + h;
        int spk = (vv >= 1.0) ? 1 : 0;
        v = vv - (double)spk;
        float gs = ge * (float)spk;
        gs += __shfl_xor(gs, 1);
        gs += __shfl_xor(gs, 2);
        gs += __shfl_xor(gs, 4);
        gacc += gs;
        int cnt = spk;
        cnt += __shfl_xor(cnt, 1);
        cnt += __shfl_xor(cnt, 2);
        cnt += __shfl_xor(cnt, 4);
        if (e == 0) {
            int mp = bg * 16 + t;
            int lane_a = (mp & 31) + 32 * qd_a;
            Cf[(((size_t)kb_a * MT_ALL + (mp >> 5)) * 64 + lane_a) * 16 + byte_a]
                = (char)cnt;
        }
    }
    if (e == 0) Mean[(size_t)bg * S1 + og] = gacc * 0.0625f;
}

// ---------------------------------------------------------------------------
// Generic fused stage (stages 2/3): R6's proven frag path, 4-limb, block
// 256m x 64n, shuffle recombine epilogue. Unchanged.
// ---------------------------------------------------------------------------
template<int K, int S, int SHIFT, bool WRITEC, int NBLK, int MINW>
__global__ __launch_bounds__(256, MINW) void fused_stage(
    const char* __restrict__ Ap, const char* __restrict__ Bf,
    const float* __restrict__ g, char* __restrict__ Cf,
    float* __restrict__ Mean)
{
    constexpr int KI = K / 64;
    static_assert(KI % 2 == 0, "frag path wants even KI");
    constexpr int NT = S;
    constexpr int NS = NBLK / 8;
    __shared__ double hs[256][16];           // 32 KB

    const int tid  = threadIdx.x;
    const int lane = tid & 63;
    const int w    = tid >> 6;
    const int col  = lane & 31;
    const int qd   = lane >> 5;
    const int wm   = w * 64;

    const int id    = blockIdx.x;
    const int xcd   = id & 7;
    const int inner = id >> 3;
    const int nblk  = xcd * NS + (inner >> 5);
    const int mblk  = inner & 31;
    const int m0    = mblk * 256;

    const int nt0 = nblk * 2;
    const char* Bbase = Bf + ((size_t)nt0 * 64 + lane) * 16;

    v16i acc[2][2];
    #pragma unroll
    for (int i = 0; i < 2; ++i)
        #pragma unroll
        for (int j = 0; j < 2; ++j)
            #pragma unroll
            for (int r = 0; r < 16; ++r) acc[i][j][r] = 0;

    auto loadB = [&](int kb, int jj) -> v4i {
        return *(const v4i*)(Bbase + (size_t)kb * (NT * 1024) + jj * 1024);
    };
    const int mt0 = (m0 + wm) >> 5;
    const char* Abase = Ap + ((size_t)mt0 * 64 + lane) * 16;
    auto loadA = [&](int kb, int ii) -> v4i {
        return *(const v4i*)(Abase + (size_t)kb * (MT_ALL * 1024) + ii * 1024);
    };

    v4i Ab[2][4];
    v4i Bb[2][4];

    #pragma unroll
    for (int ks = 0; ks < 2; ++ks) {
        Ab[0][ks * 2 + 0] = loadA(ks, 0);
        Ab[0][ks * 2 + 1] = loadA(ks, 1);
        #pragma unroll
        for (int jj = 0; jj < 2; ++jj)
            Bb[0][ks * 2 + jj] = loadB(ks, jj);
    }

    auto body = [&](int it, int cur, int pf) {
        const int itp = it + 1;
        #pragma unroll
        for (int ks = 0; ks < 2; ++ks) {
            Ab[pf][ks * 2 + 0] = loadA(itp * 2 + ks, 0);
            Ab[pf][ks * 2 + 1] = loadA(itp * 2 + ks, 1);
            #pragma unroll
            for (int jj = 0; jj < 2; ++jj)
                Bb[pf][ks * 2 + jj] = loadB(itp * 2 + ks, jj);
        }
        #pragma unroll
        for (int ks = 0; ks < 2; ++ks)
            #pragma unroll
            for (int jj = 0; jj < 2; ++jj) {
                acc[0][jj] = __builtin_amdgcn_mfma_i32_32x32x32_i8(Ab[cur][ks*2+0], Bb[cur][ks*2+jj], acc[0][jj], 0,0,0);
                acc[1][jj] = __builtin_amdgcn_mfma_i32_32x32x32_i8(Ab[cur][ks*2+1], Bb[cur][ks*2+jj], acc[1][jj], 0,0,0);
            }
    };
    for (int it = 0; it < KI; it += 2) {
        body(it + 0, 0, 1);
        body(it + 1, 1, 0);
    }

    // ---- limb recombine (exact): int pair-combine then one f64 fma ----
    const double sbase = 1.0 / (double)(1ll << SHIFT);
    #pragma unroll
    for (int j = 0; j < 2; ++j) {
        const int oe = j * 8 + (col >> 2);
        #pragma unroll
        for (int i = 0; i < 2; ++i) {
            #pragma unroll
            for (int reg = 0; reg < 16; ++reg) {
                int a = acc[i][j][reg];
                int s01 = a + (__shfl_xor(a, 1) << 8);
                int s23 = __shfl_xor(s01, 2);
                double d = ((double)s01 + 65536.0 * (double)s23) * sbase;
                if ((col & 3) == 0) {
                    int m = wm + i * 32 + (reg & 3) + 8 * (reg >> 2) + 4 * qd;
                    hs[m][oe] = d;
                }
            }
        }
    }
    __syncthreads();

    const int b_loc  = tid >> 4;
    const int o_loc  = (tid >> 3) & 1;
    const int e      = tid & 7;
    const int oe     = o_loc * 8 + e;
    const float ge   = g[e];
    const int bg = mblk * 16 + b_loc;
    const int og = nblk * 2 + o_loc;

    const int kb_a   = og >> 5;
    const int qd_a   = (og >> 4) & 1;
    const int byte_a = og & 15;

    double v = 0.0;
    float gacc = 0.0f;
    #pragma unroll
    for (int t = 0; t < T_STEPS; ++t) {
        double h  = hs[b_loc * 16 + t][oe];
        double vv = v * 0.95 + h;
        int spk = (vv >= 1.0) ? 1 : 0;
        v = vv - (double)spk;
        float gs = ge * (float)spk;
        gs += __shfl_xor(gs, 1);
        gs += __shfl_xor(gs, 2);
        gs += __shfl_xor(gs, 4);
        gacc += gs;
        if (WRITEC) {
            int cnt = spk;
            cnt += __shfl_xor(cnt, 1);
            cnt += __shfl_xor(cnt, 2);
            cnt += __shfl_xor(cnt, 4);
            if (e == 0) {
                int mp = bg * 16 + t;
                int lane_a = (mp & 31) + 32 * qd_a;
                Cf[(((size_t)kb_a * MT_ALL + (mp >> 5)) * 64 + lane_a) * 16 + byte_a]
                    = (char)cnt;
            }
        }
    }
    if (e == 0) Mean[(size_t)bg * S + og] = gacc * 0.0625f;
}

// ---------------------------------------------------------------------------
// ws layout (bytes), padded for clamp-free distance-1 prefetch:
//   AbitsT @ 0          : 3 MB  (region 4 MB; A prefetch <= 3.2 MB)
//   B1f    @ 4194304    : 18 MB 3-limb limb-major (region 20.97 MB >= 19.3)
//   B2f    @ 25165824   :  2 MB (region 3 MB >= 2.5 needed)
//   B3f    @ 28311552   :  1 MB (region 2 MB >= 1.3 needed)
//   c1f    @ 30408704   :  2 MB (region 4 MB >= 2.75 needed)
//   c2f    @ 34603008   :  2 MB (region 4 MB)   -> end 38797312 (37 MB)
// ---------------------------------------------------------------------------
extern "C" void kernel_launch(void* const* d_in, const int* in_sizes, int n_in,
                              void* d_out, int out_size, void* d_ws, size_t ws_size,
                              hipStream_t stream) {
    const float* x  = (const float*)d_in[0];
    const float* W1 = (const float*)d_in[1];
    const float* W2 = (const float*)d_in[2];
    const float* W3 = (const float*)d_in[3];
    const float* g1 = (const float*)d_in[4];
    const float* g2 = (const float*)d_in[5];
    const float* g3 = (const float*)d_in[6];
    float* out = (float*)d_out;

    char* ws = (char*)d_ws;
    u64*  AbitsT = (u64*)ws;
    char* B1f    = ws + 4194304ull;
    char* B2f    = ws + 25165824ull;
    char* B3f    = ws + 28311552ull;
    char* c1f    = ws + 30408704ull;
    char* c2f    = ws + 34603008ull;

    dim3 blk(256);

    // --- single precompute dispatch ---
    prep<<<98304 + 4608 + 512 + 256, blk, 0, stream>>>(
        x, W1, W2, W3, AbitsT, B1f, B2f, B3f);

    // --- stage 1: 3-limb limb-major, block 128m x 96n, 64 mblk * 64 nblk ---
    fused_stage1<<<64 * 64, blk, 0, stream>>>(AbitsT, B1f, g1, c1f, out);

    // --- stages 2/3: proven 4-limb frag path ---
    fused_stage<S1, S2, 35, true,  128, 3><<<32 * 128, blk, 0, stream>>>(
        c1f, B2f, g2, c2f, out + BATCH * S1);
    fused_stage<S2, S3, 35, false, 64, 3><<<32 * 64, blk, 0, stream>>>(
        c2f, B3f, g3, nullptr, out + BATCH * (S1 + S2));
}

// Round 10
// 449.833 us; speedup vs baseline: 1.1120x; 1.1120x over previous
//
#include <hip/hip_runtime.h>
#include <hip/hip_bf16.h>
#include <cmath>

#define T_STEPS 16
#define BATCH   512
#define N_IN    3072
#define S1      256
#define S2      256
#define S3      128
#define NEXP    8
#define M_ROWS  (T_STEPS * BATCH)   // 8192
#define MT_ALL  (M_ROWS / 32)       // 256 m-tiles

typedef int v4i  __attribute__((ext_vector_type(4)));
typedef int v16i __attribute__((ext_vector_type(16)));
typedef unsigned long long u64;
typedef unsigned int uint32;

// ---------------------------------------------------------------------------
// bit->byte unpack: 16 bits -> 16 i8 (0/1). mul-free spread.
// ---------------------------------------------------------------------------
__device__ __forceinline__ v4i unpack16_bits(uint32 w16)
{
    v4i d;
    #pragma unroll
    for (int c = 0; c < 4; ++c) {
        uint32 x = (w16 >> (4 * c)) & 0xFu;
        x = x + (x << 7);
        x = x + (x << 14);
        d[c] = (int)(x & 0x01010101u);
    }
    return d;
}

// ---------------------------------------------------------------------------
// 4-limb weight digitize (stages 2/3). B-row gr = o*32 + e*4 + limb.
// ---------------------------------------------------------------------------
template<int S, int K>
__device__ __forceinline__ void digitize_chunk(
    const float* __restrict__ W, char* __restrict__ Bf, int t)
{
    int lane16 = t & 63;
    int o  = (t >> 6) & (S - 1);
    int kb = t >> ((S == 256) ? 14 : 13);
    int r  = lane16 & 31;
    int qd = lane16 >> 5;
    int e    = r >> 2;
    int limb = r & 3;
    int k0 = kb * 32 + qd * 16;

    const float4* Wp = (const float4*)(W + ((size_t)e * S + o) * K + k0);
    char out[16];
    #pragma unroll
    for (int f4 = 0; f4 < 4; ++f4) {
        float4 w = Wp[f4];
        float ws[4] = {w.x, w.y, w.z, w.w};
        #pragma unroll
        for (int c = 0; c < 4; ++c) {
            long long q = llrint((double)ws[c] * 4294967296.0);
            int d = 0;
            #pragma unroll
            for (int l = 0; l < 4; ++l) {
                int dl = (int)((q + 128) & 255) - 128;
                q = (q - dl) >> 8;
                if (l == limb) d = dl;
            }
            out[f4 * 4 + c] = (char)d;
        }
    }
    *(v4i*)(Bf + (size_t)t * 16) = *(v4i*)out;
}

// ---------------------------------------------------------------------------
// prep: pack x bits + 3-limb LIMB-MAJOR digitize W1 + 4-limb W2/W3.
// W1 rows gr = limb*2048 + (o*8+e): the 3 limbs of one (o,e) occupy the same
// column position in 3 different n-tiles (jj = limb) -> per-lane recombine.
// ---------------------------------------------------------------------------
__global__ __launch_bounds__(256) void prep(
    const float* __restrict__ x,  const float* __restrict__ W1,
    const float* __restrict__ W2, const float* __restrict__ W3,
    u64* __restrict__ bitsT, char* __restrict__ B1f,
    char* __restrict__ B2f,  char* __restrict__ B3f)
{
    const int bid = blockIdx.x;
    const int tid = threadIdx.x;
    if (bid < 98304) {
        int gid = bid * 256 + tid;
        float v = x[gid];
        u64 m = __ballot(v >= 0.5f);
        if ((tid & 63) == 0) {
            int tb = gid / N_IN;                 // t*512 + b
            int k  = gid - tb * N_IN;
            int t  = tb >> 9;
            int b  = tb & 511;
            bitsT[(size_t)(k >> 6) * M_ROWS + (b * 16 + t)] = m;
        }
    } else if (bid < 98304 + 4608) {
        // W1 3-limb limb-major: chunks = 96 kb * 192 tiles * 64 l16
        int t    = (bid - 98304) * 256 + tid;
        int l16  = t & 63;
        int tt   = t >> 6;               // kb*192 + tile
        int tile = tt % 192;
        int kb   = tt / 192;
        int gr   = tile * 32 + (l16 & 31);
        int qd   = l16 >> 5;
        int limb = gr >> 11;             // 0..2
        int oe   = gr & 2047;
        int o    = oe >> 3;
        int e    = oe & 7;
        int k0   = kb * 32 + qd * 16;
        const float4* Wp = (const float4*)(W1 + ((size_t)e * S1 + o) * N_IN + k0);
        char out[16];
        #pragma unroll
        for (int f4 = 0; f4 < 4; ++f4) {
            float4 w = Wp[f4];
            float ws[4] = {w.x, w.y, w.z, w.w};
            #pragma unroll
            for (int c = 0; c < 4; ++c) {
                long long q = llrint((double)ws[c] * 16777216.0);
                int d0 = (int)((q + 128) & 255) - 128;
                long long q1 = (q - d0) >> 8;
                int d1 = (int)((q1 + 128) & 255) - 128;
                int d2 = (int)((q1 - d1) >> 8);
                int d  = (limb == 0) ? d0 : ((limb == 1) ? d1 : d2);
                out[f4 * 4 + c] = (char)d;
            }
        }
        *(v4i*)(B1f + (size_t)t * 16) = *(v4i*)out;
    } else if (bid < 98304 + 4608 + 512) {
        digitize_chunk<S2, S1>(W2, B2f, (bid - 98304 - 4608) * 256 + tid);
    } else {
        digitize_chunk<S3, S2>(W3, B3f, (bid - 98304 - 4608 - 512) * 256 + tid);
    }
}

// ---------------------------------------------------------------------------
// R10 stage 1: LDS-staged B (T3/T4 structure). Diagnosis R2..R9: every
// direct-load config is VMEM-return bound (~64 B/cy/CU; demand 100+) -- all
// waves re-load the same B bytes. Fix: stage each 12 KB B granule (4 kb x 3
// limbs) ONCE per block via global_load_lds (VMEM /4), consume via
// ds_read_b128 (separate 128 B/cy pipe). Counted vmcnt(7), raw s_barrier,
// double-buffered LDS union'd with the hs epilogue buffer (32 KB, 3 blk/CU).
// Wave tile 64m x 96n (12 MFMA per 96 B read); block 256m x 96n.
// Epilogue two-pass (m 0-127 then 128-255) keeps hs in double at 32 KB.
// ---------------------------------------------------------------------------
__global__ __launch_bounds__(256, 3) void fused_stage1(
    const u64* __restrict__ AT0, const char* __restrict__ Bf,
    const float* __restrict__ g, char* __restrict__ Cf,
    float* __restrict__ Mean)
{
    constexpr int NGR = (N_IN / 32) / 4;     // 24 granules of 4 kb
    __shared__ char smem[32768];
    double* hs  = (double*)smem;             // [128][32], epilogue only
    char*  Blds = smem;                      // [2][12][1024] during loop

    const int tid  = threadIdx.x;
    const int lane = tid & 63;
    const int w    = tid >> 6;
    const int col  = lane & 31;
    const int qd   = lane >> 5;
    const int sh16 = qd * 16;

    // mblk-major XCD map: 64 nblk (8/XCD), 32 mblk
    const int id    = blockIdx.x;
    const int xcd   = id & 7;
    const int inner = id >> 3;
    const int nblk  = xcd * 8 + (inner >> 5);
    const int mblk  = inner & 31;
    const int m0    = mblk * 256;

    // A: wave w owns m rows m0 + w*64 .. +63 (2 m-tiles)
    const u64* AT = AT0 + (m0 + w * 64 + col);

    // B staging: wave w stages kb-slot w of each granule, jj = 0..2.
    // source chunk byte = (kb*192 + jj*64 + nblk)*1024 + lane*16
    const char* Bsrc = Bf + (size_t)nblk * 1024 + lane * 16;
    char* Bdst0 = Blds + (w * 3) * 1024 + lane * 16;

    v16i acc[2][3];
    #pragma unroll
    for (int mt = 0; mt < 2; ++mt)
        #pragma unroll
        for (int jj = 0; jj < 3; ++jj)
            #pragma unroll
            for (int r = 0; r < 16; ++r) acc[mt][jj][r] = 0;

    u64 areg[2][4];   // [buf][kwl*2 + mt]

    auto stageB = [&](int gr, int buf) {
        const char* src = Bsrc + (size_t)(gr * 4 + w) * (192 * 1024);
        char* dst = Bdst0 + buf * 12288;
        #pragma unroll
        for (int jj = 0; jj < 3; ++jj)
            __builtin_amdgcn_global_load_lds(
                (const __attribute__((address_space(1))) uint32*)(src + jj * 65536),
                (__attribute__((address_space(3))) uint32*)(dst + jj * 1024),
                16, 0, 0);
    };
    auto loadA = [&](int gr, int buf) {
        const int kw = gr * 2;
        areg[buf][0] = AT[(size_t)kw * M_ROWS];
        areg[buf][1] = AT[(size_t)kw * M_ROWS + 32];
        areg[buf][2] = AT[(size_t)(kw + 1) * M_ROWS];
        areg[buf][3] = AT[(size_t)(kw + 1) * M_ROWS + 32];
    };

    // prologue: granule 0 in flight
    stageB(0, 0);
    loadA(0, 0);

    auto iter = [&](int gr, int cur, int pf) {
        stageB(gr + 1, pf);                  // clamp-free: buffers padded
        loadA(gr + 1, pf);
        asm volatile("s_waitcnt vmcnt(7)" ::: "memory");
        __builtin_amdgcn_sched_barrier(0);
        __builtin_amdgcn_s_barrier();        // buf[cur] staged for all waves
        const char* bb = Blds + cur * 12288 + lane * 16;
        __builtin_amdgcn_s_setprio(1);
        #pragma unroll
        for (int kbl = 0; kbl < 4; ++kbl) {
            v4i Bfr[3];
            #pragma unroll
            for (int jj = 0; jj < 3; ++jj)
                Bfr[jj] = *(const v4i*)(bb + (kbl * 3 + jj) * 1024);
            const int kwl = kbl >> 1;
            v4i af[2];
            #pragma unroll
            for (int mt = 0; mt < 2; ++mt) {
                u64 a = areg[cur][kwl * 2 + mt];
                uint32 dw = (kbl & 1) ? (uint32)(a >> 32) : (uint32)a;
                af[mt] = unpack16_bits(dw >> sh16);
            }
            #pragma unroll
            for (int mt = 0; mt < 2; ++mt)
                #pragma unroll
                for (int jj = 0; jj < 3; ++jj)
                    acc[mt][jj] = __builtin_amdgcn_mfma_i32_32x32x32_i8(
                        af[mt], Bfr[jj], acc[mt][jj], 0, 0, 0);
        }
        __builtin_amdgcn_s_setprio(0);
        __builtin_amdgcn_s_barrier();        // all waves done with buf[cur]
    };

    for (int gp = 0; gp < NGR; gp += 2) {
        iter(gp + 0, 0, 1);
        iter(gp + 1, 1, 0);
    }

    // ---- epilogue: two passes, hs (double) aliases the B staging LDS ----
    const double sc = 1.0 / 16777216.0;
    auto write_hs = [&](int wl) {
        #pragma unroll
        for (int mt = 0; mt < 2; ++mt)
            #pragma unroll
            for (int reg = 0; reg < 16; ++reg) {
                int r  = wl * 64 + mt * 32 + (reg & 3) + 8 * (reg >> 2) + 4 * qd;
                int lo = acc[mt][0][reg] + (acc[mt][1][reg] << 8);
                double d = ((double)lo + 65536.0 * (double)acc[mt][2][reg]) * sc;
                hs[r * 32 + col] = d;
            }
    };
    const int b_loc = tid >> 5;
    const int oe    = tid & 31;
    const int o_loc = oe >> 3;
    const int e     = tid & 7;
    const float ge  = g[e];
    const int og    = nblk * 4 + o_loc;
    const int kb_a   = og >> 5;
    const int qd_a   = (og >> 4) & 1;
    const int byte_a = og & 15;

    auto lif_pass = [&](int pass) {
        const int bg = mblk * 16 + pass * 8 + b_loc;
        double v = 0.0;
        float gacc = 0.0f;
        #pragma unroll
        for (int t = 0; t < T_STEPS; ++t) {
            double h  = hs[(b_loc * 16 + t) * 32 + oe];
            double vv = v * 0.95 + h;
            int spk = (vv >= 1.0) ? 1 : 0;
            v = vv - (double)spk;
            float gs = ge * (float)spk;
            gs += __shfl_xor(gs, 1);
            gs += __shfl_xor(gs, 2);
            gs += __shfl_xor(gs, 4);
            gacc += gs;
            int cnt = spk;
            cnt += __shfl_xor(cnt, 1);
            cnt += __shfl_xor(cnt, 2);
            cnt += __shfl_xor(cnt, 4);
            if (e == 0) {
                int mp = bg * 16 + t;
                int lane_a = (mp & 31) + 32 * qd_a;
                Cf[(((size_t)kb_a * MT_ALL + (mp >> 5)) * 64 + lane_a) * 16 + byte_a]
                    = (char)cnt;
            }
        }
        if (e == 0) Mean[(size_t)bg * S1 + og] = gacc * 0.0625f;
    };

    __syncthreads();
    if (w < 2) write_hs(w);
    __syncthreads();
    lif_pass(0);
    __syncthreads();
    if (w >= 2) write_hs(w - 2);
    __syncthreads();
    lif_pass(1);
}

// ---------------------------------------------------------------------------
// Generic fused stage (stages 2/3): R6/R9's proven frag path, 4-limb, block
// 256m x 64n, shuffle recombine epilogue. Unchanged.
// ---------------------------------------------------------------------------
template<int K, int S, int SHIFT, bool WRITEC, int NBLK, int MINW>
__global__ __launch_bounds__(256, MINW) void fused_stage(
    const char* __restrict__ Ap, const char* __restrict__ Bf,
    const float* __restrict__ g, char* __restrict__ Cf,
    float* __restrict__ Mean)
{
    constexpr int KI = K / 64;
    static_assert(KI % 2 == 0, "frag path wants even KI");
    constexpr int NT = S;
    constexpr int NS = NBLK / 8;
    __shared__ double hs[256][16];           // 32 KB

    const int tid  = threadIdx.x;
    const int lane = tid & 63;
    const int w    = tid >> 6;
    const int col  = lane & 31;
    const int qd   = lane >> 5;
    const int wm   = w * 64;

    const int id    = blockIdx.x;
    const int xcd   = id & 7;
    const int inner = id >> 3;
    const int nblk  = xcd * NS + (inner >> 5);
    const int mblk  = inner & 31;
    const int m0    = mblk * 256;

    const int nt0 = nblk * 2;
    const char* Bbase = Bf + ((size_t)nt0 * 64 + lane) * 16;

    v16i acc[2][2];
    #pragma unroll
    for (int i = 0; i < 2; ++i)
        #pragma unroll
        for (int j = 0; j < 2; ++j)
            #pragma unroll
            for (int r = 0; r < 16; ++r) acc[i][j][r] = 0;

    auto loadB = [&](int kb, int jj) -> v4i {
        return *(const v4i*)(Bbase + (size_t)kb * (NT * 1024) + jj * 1024);
    };
    const int mt0 = (m0 + wm) >> 5;
    const char* Abase = Ap + ((size_t)mt0 * 64 + lane) * 16;
    auto loadA = [&](int kb, int ii) -> v4i {
        return *(const v4i*)(Abase + (size_t)kb * (MT_ALL * 1024) + ii * 1024);
    };

    v4i Ab[2][4];
    v4i Bb[2][4];

    #pragma unroll
    for (int ks = 0; ks < 2; ++ks) {
        Ab[0][ks * 2 + 0] = loadA(ks, 0);
        Ab[0][ks * 2 + 1] = loadA(ks, 1);
        #pragma unroll
        for (int jj = 0; jj < 2; ++jj)
            Bb[0][ks * 2 + jj] = loadB(ks, jj);
    }

    auto body = [&](int it, int cur, int pf) {
        const int itp = it + 1;
        #pragma unroll
        for (int ks = 0; ks < 2; ++ks) {
            Ab[pf][ks * 2 + 0] = loadA(itp * 2 + ks, 0);
            Ab[pf][ks * 2 + 1] = loadA(itp * 2 + ks, 1);
            #pragma unroll
            for (int jj = 0; jj < 2; ++jj)
                Bb[pf][ks * 2 + jj] = loadB(itp * 2 + ks, jj);
        }
        #pragma unroll
        for (int ks = 0; ks < 2; ++ks)
            #pragma unroll
            for (int jj = 0; jj < 2; ++jj) {
                acc[0][jj] = __builtin_amdgcn_mfma_i32_32x32x32_i8(Ab[cur][ks*2+0], Bb[cur][ks*2+jj], acc[0][jj], 0,0,0);
                acc[1][jj] = __builtin_amdgcn_mfma_i32_32x32x32_i8(Ab[cur][ks*2+1], Bb[cur][ks*2+jj], acc[1][jj], 0,0,0);
            }
    };
    for (int it = 0; it < KI; it += 2) {
        body(it + 0, 0, 1);
        body(it + 1, 1, 0);
    }

    // ---- limb recombine (exact): int pair-combine then one f64 fma ----
    const double sbase = 1.0 / (double)(1ll << SHIFT);
    #pragma unroll
    for (int j = 0; j < 2; ++j) {
        const int oe = j * 8 + (col >> 2);
        #pragma unroll
        for (int i = 0; i < 2; ++i) {
            #pragma unroll
            for (int reg = 0; reg < 16; ++reg) {
                int a = acc[i][j][reg];
                int s01 = a + (__shfl_xor(a, 1) << 8);
                int s23 = __shfl_xor(s01, 2);
                double d = ((double)s01 + 65536.0 * (double)s23) * sbase;
                if ((col & 3) == 0) {
                    int m = wm + i * 32 + (reg & 3) + 8 * (reg >> 2) + 4 * qd;
                    hs[m][oe] = d;
                }
            }
        }
    }
    __syncthreads();

    const int b_loc  = tid >> 4;
    const int o_loc  = (tid >> 3) & 1;
    const int e      = tid & 7;
    const int oe     = o_loc * 8 + e;
    const float ge   = g[e];
    const int bg = mblk * 16 + b_loc;
    const int og = nblk * 2 + o_loc;

    const int kb_a   = og >> 5;
    const int qd_a   = (og >> 4) & 1;
    const int byte_a = og & 15;

    double v = 0.0;
    float gacc = 0.0f;
    #pragma unroll
    for (int t = 0; t < T_STEPS; ++t) {
        double h  = hs[b_loc * 16 + t][oe];
        double vv = v * 0.95 + h;
        int spk = (vv >= 1.0) ? 1 : 0;
        v = vv - (double)spk;
        float gs = ge * (float)spk;
        gs += __shfl_xor(gs, 1);
        gs += __shfl_xor(gs, 2);
        gs += __shfl_xor(gs, 4);
        gacc += gs;
        if (WRITEC) {
            int cnt = spk;
            cnt += __shfl_xor(cnt, 1);
            cnt += __shfl_xor(cnt, 2);
            cnt += __shfl_xor(cnt, 4);
            if (e == 0) {
                int mp = bg * 16 + t;
                int lane_a = (mp & 31) + 32 * qd_a;
                Cf[(((size_t)kb_a * MT_ALL + (mp >> 5)) * 64 + lane_a) * 16 + byte_a]
                    = (char)cnt;
            }
        }
    }
    if (e == 0) Mean[(size_t)bg * S + og] = gacc * 0.0625f;
}

// ---------------------------------------------------------------------------
// ws layout (bytes), padded for clamp-free prefetch/staging:
//   AbitsT @ 0          : 3 MB  (region 4 MB; A loads reach kw 49 = 3.27 MB)
//   B1f    @ 4194304    : 18 MB 3-limb limb-major (staging reaches kb 99 =
//                          19.6 MB <= region 20.97 MB)
//   B2f    @ 25165824   :  2 MB (region 3 MB >= 2.5 needed)
//   B3f    @ 28311552   :  1 MB (region 2 MB >= 1.3 needed)
//   c1f    @ 30408704   :  2 MB (region 4 MB >= 2.75 needed)
//   c2f    @ 34603008   :  2 MB (region 4 MB)   -> end 38797312 (37 MB)
// ---------------------------------------------------------------------------
extern "C" void kernel_launch(void* const* d_in, const int* in_sizes, int n_in,
                              void* d_out, int out_size, void* d_ws, size_t ws_size,
                              hipStream_t stream) {
    const float* x  = (const float*)d_in[0];
    const float* W1 = (const float*)d_in[1];
    const float* W2 = (const float*)d_in[2];
    const float* W3 = (const float*)d_in[3];
    const float* g1 = (const float*)d_in[4];
    const float* g2 = (const float*)d_in[5];
    const float* g3 = (const float*)d_in[6];
    float* out = (float*)d_out;

    char* ws = (char*)d_ws;
    u64*  AbitsT = (u64*)ws;
    char* B1f    = ws + 4194304ull;
    char* B2f    = ws + 25165824ull;
    char* B3f    = ws + 28311552ull;
    char* c1f    = ws + 30408704ull;
    char* c2f    = ws + 34603008ull;

    dim3 blk(256);

    // --- single precompute dispatch ---
    prep<<<98304 + 4608 + 512 + 256, blk, 0, stream>>>(
        x, W1, W2, W3, AbitsT, B1f, B2f, B3f);

    // --- stage 1: LDS-staged 3-limb, block 256m x 96n, 32 mblk * 64 nblk ---
    fused_stage1<<<32 * 64, blk, 0, stream>>>(AbitsT, B1f, g1, c1f, out);

    // --- stages 2/3: proven 4-limb frag path ---
    fused_stage<S1, S2, 35, true,  128, 3><<<32 * 128, blk, 0, stream>>>(
        c1f, B2f, g2, c2f, out + BATCH * S1);
    fused_stage<S2, S3, 35, false, 64, 3><<<32 * 64, blk, 0, stream>>>(
        c2f, B3f, g3, nullptr, out + BATCH * (S1 + S2));
}

// Round 11
// 442.706 us; speedup vs baseline: 1.1299x; 1.0161x over previous
//
#include <hip/hip_runtime.h>
#include <hip/hip_bf16.h>
#include <cmath>

#define T_STEPS 16
#define BATCH   512
#define N_IN    3072
#define S1      256
#define S2      256
#define S3      128
#define NEXP    8
#define M_ROWS  (T_STEPS * BATCH)   // 8192
#define MT_ALL  (M_ROWS / 32)       // 256 m-tiles

typedef int v4i  __attribute__((ext_vector_type(4)));
typedef int v16i __attribute__((ext_vector_type(16)));
typedef unsigned long long u64;
typedef unsigned int uint32;

// ---------------------------------------------------------------------------
// bit->byte unpack: 16 bits -> 16 i8 (0/1). mul-free spread.
// ---------------------------------------------------------------------------
__device__ __forceinline__ v4i unpack16_bits(uint32 w16)
{
    v4i d;
    #pragma unroll
    for (int c = 0; c < 4; ++c) {
        uint32 x = (w16 >> (4 * c)) & 0xFu;
        x = x + (x << 7);
        x = x + (x << 14);
        d[c] = (int)(x & 0x01010101u);
    }
    return d;
}

// ---------------------------------------------------------------------------
// 4-limb weight digitize (stages 2/3). B-row gr = o*32 + e*4 + limb.
// ---------------------------------------------------------------------------
template<int S, int K>
__device__ __forceinline__ void digitize_chunk(
    const float* __restrict__ W, char* __restrict__ Bf, int t)
{
    int lane16 = t & 63;
    int o  = (t >> 6) & (S - 1);
    int kb = t >> ((S == 256) ? 14 : 13);
    int r  = lane16 & 31;
    int qd = lane16 >> 5;
    int e    = r >> 2;
    int limb = r & 3;
    int k0 = kb * 32 + qd * 16;

    const float4* Wp = (const float4*)(W + ((size_t)e * S + o) * K + k0);
    char out[16];
    #pragma unroll
    for (int f4 = 0; f4 < 4; ++f4) {
        float4 w = Wp[f4];
        float ws[4] = {w.x, w.y, w.z, w.w};
        #pragma unroll
        for (int c = 0; c < 4; ++c) {
            long long q = llrint((double)ws[c] * 4294967296.0);
            int d = 0;
            #pragma unroll
            for (int l = 0; l < 4; ++l) {
                int dl = (int)((q + 128) & 255) - 128;
                q = (q - dl) >> 8;
                if (l == limb) d = dl;
            }
            out[f4 * 4 + c] = (char)d;
        }
    }
    *(v4i*)(Bf + (size_t)t * 16) = *(v4i*)out;
}

// ---------------------------------------------------------------------------
// prep: pack x bits + 3-limb LIMB-MAJOR digitize W1 + 4-limb W2/W3.
// W1 rows gr = limb*2048 + (o*8+e): the 3 limbs of one (o,e) occupy the same
// column position in 3 different n-tiles (jj = limb) -> per-lane recombine.
// ---------------------------------------------------------------------------
__global__ __launch_bounds__(256) void prep(
    const float* __restrict__ x,  const float* __restrict__ W1,
    const float* __restrict__ W2, const float* __restrict__ W3,
    u64* __restrict__ bitsT, char* __restrict__ B1f,
    char* __restrict__ B2f,  char* __restrict__ B3f)
{
    const int bid = blockIdx.x;
    const int tid = threadIdx.x;
    if (bid < 98304) {
        int gid = bid * 256 + tid;
        float v = x[gid];
        u64 m = __ballot(v >= 0.5f);
        if ((tid & 63) == 0) {
            int tb = gid / N_IN;                 // t*512 + b
            int k  = gid - tb * N_IN;
            int t  = tb >> 9;
            int b  = tb & 511;
            bitsT[(size_t)(k >> 6) * M_ROWS + (b * 16 + t)] = m;
        }
    } else if (bid < 98304 + 4608) {
        // W1 3-limb limb-major: chunks = 96 kb * 192 tiles * 64 l16
        int t    = (bid - 98304) * 256 + tid;
        int l16  = t & 63;
        int tt   = t >> 6;               // kb*192 + tile
        int tile = tt % 192;
        int kb   = tt / 192;
        int gr   = tile * 32 + (l16 & 31);
        int qd   = l16 >> 5;
        int limb = gr >> 11;             // 0..2
        int oe   = gr & 2047;
        int o    = oe >> 3;
        int e    = oe & 7;
        int k0   = kb * 32 + qd * 16;
        const float4* Wp = (const float4*)(W1 + ((size_t)e * S1 + o) * N_IN + k0);
        char out[16];
        #pragma unroll
        for (int f4 = 0; f4 < 4; ++f4) {
            float4 w = Wp[f4];
            float ws[4] = {w.x, w.y, w.z, w.w};
            #pragma unroll
            for (int c = 0; c < 4; ++c) {
                long long q = llrint((double)ws[c] * 16777216.0);
                int d0 = (int)((q + 128) & 255) - 128;
                long long q1 = (q - d0) >> 8;
                int d1 = (int)((q1 + 128) & 255) - 128;
                int d2 = (int)((q1 - d1) >> 8);
                int d  = (limb == 0) ? d0 : ((limb == 1) ? d1 : d2);
                out[f4 * 4 + c] = (char)d;
            }
        }
        *(v4i*)(B1f + (size_t)t * 16) = *(v4i*)out;
    } else if (bid < 98304 + 4608 + 512) {
        digitize_chunk<S2, S1>(W2, B2f, (bid - 98304 - 4608) * 256 + tid);
    } else {
        digitize_chunk<S3, S2>(W3, B3f, (bid - 98304 - 4608 - 512) * 256 + tid);
    }
}

// ---------------------------------------------------------------------------
// R11 stage 1: LDS-staged A AND B. R10 (LDS-staged B) broke the VMEM-return
// plateau: 218 -> 155 us, MfmaUtil 32 -> 45%. Remaining gap to the 70 us
// MFMA floor is occupancy: 76 VGPR + 96 AGPR acc = 172 unified -> alloc 176
// -> only 2 blocks/CU; 2-barrier bubbles can't fill the MFMA pipe.
// R11 shaves the A double-buffer registers (16 VGPR) by staging the 4 KB
// A-bit slice per granule through LDS with one extra global_load_lds per
// wave; per-lane u64 read back inside the compute phase (broadcast across
// qd halves, 2-way-conflict b64 reads = free). Target ~160 unified -> 3
// blocks/CU. LDS = 2 x (12 KB B + 4 KB A) = 32 KB, union'd with hs.
// Counted vmcnt(4) (4 loads/wave/iter, distance-1), raw barriers.
// ---------------------------------------------------------------------------
__global__ __launch_bounds__(256, 3) void fused_stage1(
    const u64* __restrict__ AT0, const char* __restrict__ Bf,
    const float* __restrict__ g, char* __restrict__ Cf,
    float* __restrict__ Mean)
{
    constexpr int NGR = (N_IN / 32) / 4;     // 24 granules of 4 kb
    __shared__ char smem[32768];
    double* hs  = (double*)smem;             // [128][32], epilogue only
    char*  Blds = smem;                      // [2][12][1024] B staging
    char*  Alds = smem + 24576;              // [2][4096]   A bits staging

    const int tid  = threadIdx.x;
    const int lane = tid & 63;
    const int w    = tid >> 6;
    const int col  = lane & 31;
    const int qd   = lane >> 5;
    const int sh16 = qd * 16;

    // mblk-major XCD map: 64 nblk (8/XCD), 32 mblk
    const int id    = blockIdx.x;
    const int xcd   = id & 7;
    const int inner = id >> 3;
    const int nblk  = xcd * 8 + (inner >> 5);
    const int mblk  = inner & 31;
    const int m0    = mblk * 256;

    // B staging: wave w stages kb-slot w of each granule, jj = 0..2.
    const char* Bsrc = Bf + (size_t)nblk * 1024 + lane * 16;
    char* Bdst0 = Blds + (w * 3) * 1024 + lane * 16;

    // A staging: granule slice = rows m0..m0+255 for kw0,kw1 (2 KB each).
    // waves 0,1 stage kw0 halves; waves 2,3 stage kw1 halves. Linear dest.
    const char* Asrc = (const char*)AT0 + (size_t)m0 * 8
                       + (w & 1) * 1024 + lane * 16;
    char* Adst = Alds + (w >> 1) * 2048 + (w & 1) * 1024 + lane * 16;

    v16i acc[2][3];
    #pragma unroll
    for (int mt = 0; mt < 2; ++mt)
        #pragma unroll
        for (int jj = 0; jj < 3; ++jj)
            #pragma unroll
            for (int r = 0; r < 16; ++r) acc[mt][jj][r] = 0;

    auto stageB = [&](int gr, int buf) {
        const char* src = Bsrc + (size_t)(gr * 4 + w) * (192 * 1024);
        char* dst = Bdst0 + buf * 12288;
        #pragma unroll
        for (int jj = 0; jj < 3; ++jj)
            __builtin_amdgcn_global_load_lds(
                (const __attribute__((address_space(1))) uint32*)(src + jj * 65536),
                (__attribute__((address_space(3))) uint32*)(dst + jj * 1024),
                16, 0, 0);
    };
    auto stageA = [&](int gr, int buf) {
        const char* src = Asrc + (size_t)(gr * 2 + (w >> 1)) * 65536;
        __builtin_amdgcn_global_load_lds(
            (const __attribute__((address_space(1))) uint32*)src,
            (__attribute__((address_space(3))) uint32*)(Adst + buf * 4096),
            16, 0, 0);
    };

    // prologue: granule 0 in flight (4 loads per wave)
    stageB(0, 0);
    stageA(0, 0);

    auto iter = [&](int gr, int cur, int pf) {
        stageB(gr + 1, pf);                  // clamp-free: buffers padded
        stageA(gr + 1, pf);
        asm volatile("s_waitcnt vmcnt(4)" ::: "memory");
        __builtin_amdgcn_sched_barrier(0);
        __builtin_amdgcn_s_barrier();        // buf[cur] staged for all waves
        const char* bb = Blds + cur * 12288 + lane * 16;
        const char* aa = Alds + cur * 4096 + (w * 64 + col) * 8;
        u64 a0[2], a1[2];                    // [kw]: rows col, col+32
        a0[0] = *(const u64*)(aa);
        a1[0] = *(const u64*)(aa + 256);
        a0[1] = *(const u64*)(aa + 2048);
        a1[1] = *(const u64*)(aa + 2048 + 256);
        __builtin_amdgcn_s_setprio(1);
        #pragma unroll
        for (int kbl = 0; kbl < 4; ++kbl) {
            v4i Bfr[3];
            #pragma unroll
            for (int jj = 0; jj < 3; ++jj)
                Bfr[jj] = *(const v4i*)(bb + (kbl * 3 + jj) * 1024);
            const int kw = kbl >> 1;
            uint32 dw0 = (kbl & 1) ? (uint32)(a0[kw] >> 32) : (uint32)a0[kw];
            uint32 dw1 = (kbl & 1) ? (uint32)(a1[kw] >> 32) : (uint32)a1[kw];
            v4i af0 = unpack16_bits(dw0 >> sh16);
            v4i af1 = unpack16_bits(dw1 >> sh16);
            #pragma unroll
            for (int jj = 0; jj < 3; ++jj) {
                acc[0][jj] = __builtin_amdgcn_mfma_i32_32x32x32_i8(
                    af0, Bfr[jj], acc[0][jj], 0, 0, 0);
                acc[1][jj] = __builtin_amdgcn_mfma_i32_32x32x32_i8(
                    af1, Bfr[jj], acc[1][jj], 0, 0, 0);
            }
        }
        __builtin_amdgcn_s_setprio(0);
        __builtin_amdgcn_s_barrier();        // all waves done with buf[cur]
    };

    for (int gp = 0; gp < NGR; gp += 2) {
        iter(gp + 0, 0, 1);
        iter(gp + 1, 1, 0);
    }

    // ---- epilogue: two passes, hs (double) aliases the staging LDS ----
    const double sc = 1.0 / 16777216.0;
    auto write_hs = [&](int wl) {
        #pragma unroll
        for (int mt = 0; mt < 2; ++mt)
            #pragma unroll
            for (int reg = 0; reg < 16; ++reg) {
                int r  = wl * 64 + mt * 32 + (reg & 3) + 8 * (reg >> 2) + 4 * qd;
                int lo = acc[mt][0][reg] + (acc[mt][1][reg] << 8);
                double d = ((double)lo + 65536.0 * (double)acc[mt][2][reg]) * sc;
                hs[r * 32 + col] = d;
            }
    };
    const int b_loc = tid >> 5;
    const int oe    = tid & 31;
    const int o_loc = oe >> 3;
    const int e     = tid & 7;
    const float ge  = g[e];
    const int og    = nblk * 4 + o_loc;
    const int kb_a   = og >> 5;
    const int qd_a   = (og >> 4) & 1;
    const int byte_a = og & 15;

    auto lif_pass = [&](int pass) {
        const int bg = mblk * 16 + pass * 8 + b_loc;
        double v = 0.0;
        float gacc = 0.0f;
        #pragma unroll
        for (int t = 0; t < T_STEPS; ++t) {
            double h  = hs[(b_loc * 16 + t) * 32 + oe];
            double vv = v * 0.95 + h;
            int spk = (vv >= 1.0) ? 1 : 0;
            v = vv - (double)spk;
            float gs = ge * (float)spk;
            gs += __shfl_xor(gs, 1);
            gs += __shfl_xor(gs, 2);
            gs += __shfl_xor(gs, 4);
            gacc += gs;
            int cnt = spk;
            cnt += __shfl_xor(cnt, 1);
            cnt += __shfl_xor(cnt, 2);
            cnt += __shfl_xor(cnt, 4);
            if (e == 0) {
                int mp = bg * 16 + t;
                int lane_a = (mp & 31) + 32 * qd_a;
                Cf[(((size_t)kb_a * MT_ALL + (mp >> 5)) * 64 + lane_a) * 16 + byte_a]
                    = (char)cnt;
            }
        }
        if (e == 0) Mean[(size_t)bg * S1 + og] = gacc * 0.0625f;
    };

    __syncthreads();
    if (w < 2) write_hs(w);
    __syncthreads();
    lif_pass(0);
    __syncthreads();
    if (w >= 2) write_hs(w - 2);
    __syncthreads();
    lif_pass(1);
}

// ---------------------------------------------------------------------------
// Generic fused stage (stages 2/3): R6/R9's proven frag path, 4-limb, block
// 256m x 64n, shuffle recombine epilogue. Unchanged.
// ---------------------------------------------------------------------------
template<int K, int S, int SHIFT, bool WRITEC, int NBLK, int MINW>
__global__ __launch_bounds__(256, MINW) void fused_stage(
    const char* __restrict__ Ap, const char* __restrict__ Bf,
    const float* __restrict__ g, char* __restrict__ Cf,
    float* __restrict__ Mean)
{
    constexpr int KI = K / 64;
    static_assert(KI % 2 == 0, "frag path wants even KI");
    constexpr int NT = S;
    constexpr int NS = NBLK / 8;
    __shared__ double hs[256][16];           // 32 KB

    const int tid  = threadIdx.x;
    const int lane = tid & 63;
    const int w    = tid >> 6;
    const int col  = lane & 31;
    const int qd   = lane >> 5;
    const int wm   = w * 64;

    const int id    = blockIdx.x;
    const int xcd   = id & 7;
    const int inner = id >> 3;
    const int nblk  = xcd * NS + (inner >> 5);
    const int mblk  = inner & 31;
    const int m0    = mblk * 256;

    const int nt0 = nblk * 2;
    const char* Bbase = Bf + ((size_t)nt0 * 64 + lane) * 16;

    v16i acc[2][2];
    #pragma unroll
    for (int i = 0; i < 2; ++i)
        #pragma unroll
        for (int j = 0; j < 2; ++j)
            #pragma unroll
            for (int r = 0; r < 16; ++r) acc[i][j][r] = 0;

    auto loadB = [&](int kb, int jj) -> v4i {
        return *(const v4i*)(Bbase + (size_t)kb * (NT * 1024) + jj * 1024);
    };
    const int mt0 = (m0 + wm) >> 5;
    const char* Abase = Ap + ((size_t)mt0 * 64 + lane) * 16;
    auto loadA = [&](int kb, int ii) -> v4i {
        return *(const v4i*)(Abase + (size_t)kb * (MT_ALL * 1024) + ii * 1024);
    };

    v4i Ab[2][4];
    v4i Bb[2][4];

    #pragma unroll
    for (int ks = 0; ks < 2; ++ks) {
        Ab[0][ks * 2 + 0] = loadA(ks, 0);
        Ab[0][ks * 2 + 1] = loadA(ks, 1);
        #pragma unroll
        for (int jj = 0; jj < 2; ++jj)
            Bb[0][ks * 2 + jj] = loadB(ks, jj);
    }

    auto body = [&](int it, int cur, int pf) {
        const int itp = it + 1;
        #pragma unroll
        for (int ks = 0; ks < 2; ++ks) {
            Ab[pf][ks * 2 + 0] = loadA(itp * 2 + ks, 0);
            Ab[pf][ks * 2 + 1] = loadA(itp * 2 + ks, 1);
            #pragma unroll
            for (int jj = 0; jj < 2; ++jj)
                Bb[pf][ks * 2 + jj] = loadB(itp * 2 + ks, jj);
        }
        #pragma unroll
        for (int ks = 0; ks < 2; ++ks)
            #pragma unroll
            for (int jj = 0; jj < 2; ++jj) {
                acc[0][jj] = __builtin_amdgcn_mfma_i32_32x32x32_i8(Ab[cur][ks*2+0], Bb[cur][ks*2+jj], acc[0][jj], 0,0,0);
                acc[1][jj] = __builtin_amdgcn_mfma_i32_32x32x32_i8(Ab[cur][ks*2+1], Bb[cur][ks*2+jj], acc[1][jj], 0,0,0);
            }
    };
    for (int it = 0; it < KI; it += 2) {
        body(it + 0, 0, 1);
        body(it + 1, 1, 0);
    }

    // ---- limb recombine (exact): int pair-combine then one f64 fma ----
    const double sbase = 1.0 / (double)(1ll << SHIFT);
    #pragma unroll
    for (int j = 0; j < 2; ++j) {
        const int oe = j * 8 + (col >> 2);
        #pragma unroll
        for (int i = 0; i < 2; ++i) {
            #pragma unroll
            for (int reg = 0; reg < 16; ++reg) {
                int a = acc[i][j][reg];
                int s01 = a + (__shfl_xor(a, 1) << 8);
                int s23 = __shfl_xor(s01, 2);
                double d = ((double)s01 + 65536.0 * (double)s23) * sbase;
                if ((col & 3) == 0) {
                    int m = wm + i * 32 + (reg & 3) + 8 * (reg >> 2) + 4 * qd;
                    hs[m][oe] = d;
                }
            }
        }
    }
    __syncthreads();

    const int b_loc  = tid >> 4;
    const int o_loc  = (tid >> 3) & 1;
    const int e      = tid & 7;
    const int oe     = o_loc * 8 + e;
    const float ge   = g[e];
    const int bg = mblk * 16 + b_loc;
    const int og = nblk * 2 + o_loc;

    const int kb_a   = og >> 5;
    const int qd_a   = (og >> 4) & 1;
    const int byte_a = og & 15;

    double v = 0.0;
    float gacc = 0.0f;
    #pragma unroll
    for (int t = 0; t < T_STEPS; ++t) {
        double h  = hs[b_loc * 16 + t][oe];
        double vv = v * 0.95 + h;
        int spk = (vv >= 1.0) ? 1 : 0;
        v = vv - (double)spk;
        float gs = ge * (float)spk;
        gs += __shfl_xor(gs, 1);
        gs += __shfl_xor(gs, 2);
        gs += __shfl_xor(gs, 4);
        gacc += gs;
        if (WRITEC) {
            int cnt = spk;
            cnt += __shfl_xor(cnt, 1);
            cnt += __shfl_xor(cnt, 2);
            cnt += __shfl_xor(cnt, 4);
            if (e == 0) {
                int mp = bg * 16 + t;
                int lane_a = (mp & 31) + 32 * qd_a;
                Cf[(((size_t)kb_a * MT_ALL + (mp >> 5)) * 64 + lane_a) * 16 + byte_a]
                    = (char)cnt;
            }
        }
    }
    if (e == 0) Mean[(size_t)bg * S + og] = gacc * 0.0625f;
}

// ---------------------------------------------------------------------------
// ws layout (bytes), padded for clamp-free prefetch/staging:
//   AbitsT @ 0          : 3 MB  (region 4 MB; A staging reaches kw 49 + 66KB)
//   B1f    @ 4194304    : 18 MB 3-limb limb-major (staging reaches kb 99 =
//                          19.6 MB <= region 20.97 MB)
//   B2f    @ 25165824   :  2 MB (region 3 MB >= 2.5 needed)
//   B3f    @ 28311552   :  1 MB (region 2 MB >= 1.3 needed)
//   c1f    @ 30408704   :  2 MB (region 4 MB >= 2.75 needed)
//   c2f    @ 34603008   :  2 MB (region 4 MB)   -> end 38797312 (37 MB)
// ---------------------------------------------------------------------------
extern "C" void kernel_launch(void* const* d_in, const int* in_sizes, int n_in,
                              void* d_out, int out_size, void* d_ws, size_t ws_size,
                              hipStream_t stream) {
    const float* x  = (const float*)d_in[0];
    const float* W1 = (const float*)d_in[1];
    const float* W2 = (const float*)d_in[2];
    const float* W3 = (const float*)d_in[3];
    const float* g1 = (const float*)d_in[4];
    const float* g2 = (const float*)d_in[5];
    const float* g3 = (const float*)d_in[6];
    float* out = (float*)d_out;

    char* ws = (char*)d_ws;
    u64*  AbitsT = (u64*)ws;
    char* B1f    = ws + 4194304ull;
    char* B2f    = ws + 25165824ull;
    char* B3f    = ws + 28311552ull;
    char* c1f    = ws + 30408704ull;
    char* c2f    = ws + 34603008ull;

    dim3 blk(256);

    // --- single precompute dispatch ---
    prep<<<98304 + 4608 + 512 + 256, blk, 0, stream>>>(
        x, W1, W2, W3, AbitsT, B1f, B2f, B3f);

    // --- stage 1: LDS-staged A+B 3-limb, block 256m x 96n, 32x64 grid ---
    fused_stage1<<<32 * 64, blk, 0, stream>>>(AbitsT, B1f, g1, c1f, out);

    // --- stages 2/3: proven 4-limb frag path ---
    fused_stage<S1, S2, 35, true,  128, 3><<<32 * 128, blk, 0, stream>>>(
        c1f, B2f, g2, c2f, out + BATCH * S1);
    fused_stage<S2, S3, 35, false, 64, 3><<<32 * 64, blk, 0, stream>>>(
        c2f, B3f, g3, nullptr, out + BATCH * (S1 + S2));
}